// Round 8
// baseline (1073.968 us; speedup 1.0000x reference)
//
#include <hip/hip_runtime.h>
#include <hip/hip_bf16.h>
#include <math.h>

typedef __hip_bfloat16 bf16;
typedef unsigned short u16;
typedef __bf16 bf16x8 __attribute__((ext_vector_type(8)));
typedef float f32x4 __attribute__((ext_vector_type(4)));

// ---------- helpers ----------
__device__ __forceinline__ float b2f(bf16 v) { return __bfloat162float(v); }
__device__ __forceinline__ bf16 f2b(float v) { return __float2bfloat16(v); }
__device__ __forceinline__ float bits2f(unsigned int u) {
    union { unsigned int i; float f; } w; w.i = u << 16; return w.f;
}
__device__ __forceinline__ u16 f2bits(float v) {
    union { bf16 h; u16 u; } w; w.h = __float2bfloat16(v); return w.u;
}
__device__ __forceinline__ void async16(void* lds, const void* g) {
    __builtin_amdgcn_global_load_lds(
        (const __attribute__((address_space(1))) unsigned int*)g,
        (__attribute__((address_space(3))) unsigned int*)lds, 16, 0, 0);
}
// tanh-form gelu (|exact-this| <= ~3e-3, safe under 2% threshold)
__device__ __forceinline__ float fast_gelu(float x) {
    const float u = 0.7978845608f * (x + 0.044715f * x * x * x);
    const float a = fabsf(u);
    const float e = __expf(-2.0f * a);
    float t = (1.0f - e) / (1.0f + e);
    t = copysignf(t, u);
    return 0.5f * x * (1.0f + t);
}

#define DEPTH 4
#define HEADS 8
#define DHEAD 64
#define DIM 512
#define MLPD 2048
#define RED 128
#define BB 8
#define PP 4
#define NN 256
#define ROWS (BB*PP*NN)          // 8192 tokens
#define XELEMS ((size_t)ROWS*DIM) // 4194304

// ---------- batched weight transpose+cast: W fp32 [D][K][N] -> WT bf16 [D][N][K] ----------
__global__ __launch_bounds__(256)
void wtrans_all(const float* __restrict__ W, u16* __restrict__ WT, int K, int N)
{
    __shared__ float T[32][33];
    const int l = blockIdx.z;
    W  += (size_t)l * K * N;
    WT += (size_t)l * N * K;
    const int tx = threadIdx.x & 31, ty = threadIdx.x >> 5;
    const int n0 = blockIdx.x * 32, k0 = blockIdx.y * 32;
#pragma unroll
    for (int r = 0; r < 4; ++r)
        T[ty + r*8][tx] = W[(size_t)(k0 + ty + r*8) * N + n0 + tx];
    __syncthreads();
#pragma unroll
    for (int r = 0; r < 4; ++r)
        WT[(size_t)(n0 + ty + r*8) * K + k0 + tx] = f2bits(T[tx][ty + r*8]);
}

// ---------- double-buffered MFMA GEMM with LDS-transposed vector epilogue ----------
// C = act(A @ WT^T + bias) [+res]; A bf16 [M,K], WT bf16 [N,K].
// blockIdx.x = M-tile (XCD locality for A), blockIdx.y = N-tile.
// Requires WROWS==2 (epilogue processes C in two row-halves inside staging LDS).
// ACT: 0 none, 1 gelu, 2 sigmoid. OUTF32: fp32 C (else bf16).
template<int BM, int BN, int BK, int WCOLS, int OUTF32, int ACT>
__global__ __launch_bounds__(256)
void gemm_db(const u16* __restrict__ A, const u16* __restrict__ WT,
             const float* __restrict__ bias, const float* __restrict__ res,
             void* __restrict__ Cv, int M, int N, int K)
{
    constexpr int KG  = BK/8;
    constexpr int RPC = 512/BK;
    constexpr int NCA = BM*BK/512;
    constexpr int NCB = BN*BK/512;
    constexpr int CPT = (NCA+NCB)/4;
    constexpr int WM = BM/2, WN = BN/WCOLS;
    constexpr int AM = WM/16, AN = WN/16, KB = BK/32;
    constexpr int HROWS = BM/2;                      // rows per epilogue half
    constexpr int CP = OUTF32 ? (BN + 8) : (BN + 16);
    constexpr int SBYTES = 2*(BM+BN)*BK*2;           // staging footprint only
    static_assert(HROWS*CP*(OUTF32?4:2) <= SBYTES, "C half-tile must fit in staging LDS");

    __shared__ __align__(16) char SMEM[SBYTES];
    u16* As = (u16*)SMEM;                    // 2 x BM*BK
    u16* Bs = (u16*)SMEM + 2*BM*BK;          // 2 x BN*BK

    const int tid = threadIdx.x, wave = tid >> 6, lane = tid & 63;
    const int bm = blockIdx.x * BM;
    const int bn = blockIdx.y * BN;
    const int wm = (wave / WCOLS) * WM, wn = (wave % WCOLS) * WN;
    const int lr = lane & 15, quad = lane >> 4;

    const int rowc = lane / KG;
    const int kgs  = ((lane & (KG-1)) ^ (KG == 4 ? ((rowc >> 1) & 3) : (rowc & 7))) * 8;

    auto stage = [&](int buf, int k0) {
#pragma unroll
        for (int t = 0; t < CPT; ++t) {
            const int c = wave*CPT + t;
            if (c < NCA)
                async16(As + buf*BM*BK + c*512, A  + (size_t)(bm + c*RPC + rowc) * K + k0 + kgs);
            else
                async16(Bs + buf*BN*BK + (c-NCA)*512, WT + (size_t)(bn + (c-NCA)*RPC + rowc) * K + k0 + kgs);
        }
    };

    f32x4 acc[AM][AN] = {};

    stage(0, 0);
    __syncthreads();

    const int NK = K / BK;
    for (int ki = 0; ki < NK; ++ki) {
        const int cur = ki & 1;
        if (ki + 1 < NK) stage(cur ^ 1, (ki + 1) * BK);

        bf16x8 af[AM][KB], bv[AN][KB];
#pragma unroll
        for (int i = 0; i < AM; ++i) {
            const int rA = wm + i*16 + lr;
            const int sw = (KG == 4 ? (((rA & 15) >> 1) & 3) : (rA & 7));
#pragma unroll
            for (int kb = 0; kb < KB; ++kb)
                af[i][kb] = *(const bf16x8*)(As + cur*BM*BK + rA*BK + (((kb*4 + quad) ^ sw) * 8));
        }
#pragma unroll
        for (int j = 0; j < AN; ++j) {
            const int rB = wn + j*16 + lr;
            const int sw = (KG == 4 ? (((rB & 15) >> 1) & 3) : (rB & 7));
#pragma unroll
            for (int kb = 0; kb < KB; ++kb)
                bv[j][kb] = *(const bf16x8*)(Bs + cur*BN*BK + rB*BK + (((kb*4 + quad) ^ sw) * 8));
        }
#pragma unroll
        for (int i = 0; i < AM; ++i)
#pragma unroll
            for (int j = 0; j < AN; ++j)
#pragma unroll
                for (int kb = 0; kb < KB; ++kb)
                    acc[i][j] = __builtin_amdgcn_mfma_f32_16x16x32_bf16(
                        af[i][kb], bv[j][kb], acc[i][j], 0, 0, 0);
        __syncthreads();
    }

    // ---- epilogue: two row-halves; each: act(acc+bias) -> padded LDS -> vector stores ----
#pragma unroll
    for (int half = 0; half < 2; ++half) {
        // write phase: waves whose rows fall in this half
        if (wm / HROWS == half) {
            const int rbase = wm % HROWS;
#pragma unroll
            for (int i = 0; i < AM; ++i) {
                const int rloc = rbase + i*16 + quad*4;
#pragma unroll
                for (int j = 0; j < AN; ++j) {
                    const int cloc = wn + j*16 + lr;
                    const float bvs = bias ? bias[bn + cloc] : 0.f;
#pragma unroll
                    for (int r = 0; r < 4; ++r) {
                        float v = acc[i][j][r] + bvs;
                        if (ACT == 1) v = fast_gelu(v);
                        else if (ACT == 2) v = 1.0f / (1.0f + __expf(-v));
                        if (OUTF32) ((float*)SMEM)[(rloc + r)*CP + cloc] = v;
                        else        ((u16*)SMEM)[(rloc + r)*CP + cloc] = f2bits(v);
                    }
                }
            }
        }
        __syncthreads();
        // store phase: all threads copy this half out coalesced
        if (OUTF32) {
            const float* Cs = (const float*)SMEM;
            for (int e = tid*4; e < HROWS*BN; e += 1024) {
                const int row = e / BN, col = e % BN;
                float4 v = *(const float4*)(Cs + row*CP + col);
                const size_t gidx = (size_t)(bm + half*HROWS + row) * N + bn + col;
                if (res) {
                    const float4 rv = *(const float4*)(res + gidx);
                    v.x += rv.x; v.y += rv.y; v.z += rv.z; v.w += rv.w;
                }
                *(float4*)((float*)Cv + gidx) = v;
            }
        } else {
            const u16* Cs = (const u16*)SMEM;
            for (int e = tid*8; e < HROWS*BN; e += 2048) {
                const int row = e / BN, col = e % BN;
                uint4 v = *(const uint4*)(Cs + row*CP + col);
                *(uint4*)((u16*)Cv + (size_t)(bm + half*HROWS + row) * N + bn + col) = v;
            }
        }
        __syncthreads();   // half buffer free for reuse
    }
}

// ---------- MFMA flash attention: one block per (b,p,h), wave = 64 query rows ----------
__global__ __launch_bounds__(256)
void attn_mfma(const u16* __restrict__ qkv, u16* __restrict__ out)
{
    __shared__ u16 Kt[64*72];
    __shared__ u16 Vt[64*72];
    __shared__ u16 Pw[4][64*72];
    const int tid = threadIdx.x;
    const int wave = tid >> 6, lane = tid & 63;
    const int lr = lane & 15, quad = lane >> 4;
    const int bp = blockIdx.x >> 3, h = blockIdx.x & 7;
    const u16* base = qkv + (size_t)bp * NN * (3*DIM);
    const int qo = h*DHEAD, ko = DIM + h*DHEAD, vo = 2*DIM + h*DHEAD;
    const int m0 = wave * 64;

    bf16x8 qf[4][2];
#pragma unroll
    for (int i = 0; i < 4; ++i)
#pragma unroll
        for (int kb = 0; kb < 2; ++kb)
            qf[i][kb] = *(const bf16x8*)(base + (size_t)(m0 + i*16 + lr)*(3*DIM)
                                         + qo + kb*32 + quad*8);

    f32x4 o[4][4] = {};
    float mrow[4][4], lrow[4][4];
#pragma unroll
    for (int i = 0; i < 4; ++i)
#pragma unroll
        for (int r = 0; r < 4; ++r) { mrow[i][r] = -1e30f; lrow[i][r] = 0.f; }

    const int sr = tid >> 3, sc = tid & 7;

    for (int t = 0; t < 4; ++t) {
        __syncthreads();
#pragma unroll
        for (int half = 0; half < 2; ++half) {
            const int key = half*32 + sr;
            const u16* krow = base + (size_t)(t*64 + key)*(3*DIM);
            uint4 kv = *(const uint4*)(krow + ko + sc*8);
            *(uint4*)(Kt + key*72 + sc*8) = kv;
            uint4 vv = *(const uint4*)(krow + vo + sc*8);
            const int d0 = sc*8;
            Vt[(d0+0)*72 + key] = (u16)(vv.x & 0xffffu);
            Vt[(d0+1)*72 + key] = (u16)(vv.x >> 16);
            Vt[(d0+2)*72 + key] = (u16)(vv.y & 0xffffu);
            Vt[(d0+3)*72 + key] = (u16)(vv.y >> 16);
            Vt[(d0+4)*72 + key] = (u16)(vv.z & 0xffffu);
            Vt[(d0+5)*72 + key] = (u16)(vv.z >> 16);
            Vt[(d0+6)*72 + key] = (u16)(vv.w & 0xffffu);
            Vt[(d0+7)*72 + key] = (u16)(vv.w >> 16);
        }
        __syncthreads();

        f32x4 s[4][4] = {};
        bf16x8 kf[4][2];
#pragma unroll
        for (int j = 0; j < 4; ++j)
#pragma unroll
            for (int kb = 0; kb < 2; ++kb)
                kf[j][kb] = *(const bf16x8*)(Kt + (j*16 + lr)*72 + kb*32 + quad*8);
#pragma unroll
        for (int i = 0; i < 4; ++i)
#pragma unroll
            for (int j = 0; j < 4; ++j)
#pragma unroll
                for (int kb = 0; kb < 2; ++kb)
                    s[i][j] = __builtin_amdgcn_mfma_f32_16x16x32_bf16(
                        qf[i][kb], kf[j][kb], s[i][j], 0, 0, 0);

        float alpha[4][4];
#pragma unroll
        for (int i = 0; i < 4; ++i)
#pragma unroll
            for (int r = 0; r < 4; ++r) {
#pragma unroll
                for (int j = 0; j < 4; ++j) s[i][j][r] *= 0.125f;
                float mt = fmaxf(fmaxf(s[i][0][r], s[i][1][r]),
                                 fmaxf(s[i][2][r], s[i][3][r]));
#pragma unroll
                for (int off = 1; off <= 8; off <<= 1) mt = fmaxf(mt, __shfl_xor(mt, off));
                const float mn = fmaxf(mrow[i][r], mt);
                alpha[i][r] = __expf(mrow[i][r] - mn);
                mrow[i][r] = mn;
                float ssum = 0.f;
#pragma unroll
                for (int j = 0; j < 4; ++j) {
                    const float p = __expf(s[i][j][r] - mn);
                    s[i][j][r] = p; ssum += p;
                }
#pragma unroll
                for (int off = 1; off <= 8; off <<= 1) ssum += __shfl_xor(ssum, off);
                lrow[i][r] = lrow[i][r]*alpha[i][r] + ssum;
            }

#pragma unroll
        for (int i = 0; i < 4; ++i)
#pragma unroll
            for (int j = 0; j < 4; ++j)
#pragma unroll
                for (int r = 0; r < 4; ++r)
                    Pw[wave][(i*16 + quad*4 + r)*72 + j*16 + lr] = f2bits(s[i][j][r]);
        __syncthreads();

#pragma unroll
        for (int i = 0; i < 4; ++i)
#pragma unroll
            for (int jd = 0; jd < 4; ++jd)
#pragma unroll
                for (int r = 0; r < 4; ++r) o[i][jd][r] *= alpha[i][r];

        bf16x8 af[4][2], bv[4][2];
#pragma unroll
        for (int i = 0; i < 4; ++i)
#pragma unroll
            for (int kb = 0; kb < 2; ++kb)
                af[i][kb] = *(const bf16x8*)(Pw[wave] + (i*16 + lr)*72 + kb*32 + quad*8);
#pragma unroll
        for (int jd = 0; jd < 4; ++jd)
#pragma unroll
            for (int kb = 0; kb < 2; ++kb)
                bv[jd][kb] = *(const bf16x8*)(Vt + (jd*16 + lr)*72 + kb*32 + quad*8);
#pragma unroll
        for (int i = 0; i < 4; ++i)
#pragma unroll
            for (int jd = 0; jd < 4; ++jd)
#pragma unroll
                for (int kb = 0; kb < 2; ++kb)
                    o[i][jd] = __builtin_amdgcn_mfma_f32_16x16x32_bf16(
                        af[i][kb], bv[jd][kb], o[i][jd], 0, 0, 0);
    }

#pragma unroll
    for (int i = 0; i < 4; ++i)
#pragma unroll
        for (int r = 0; r < 4; ++r) {
            const float inv = 1.0f / lrow[i][r];
            const size_t rowg = (size_t)bp*NN + m0 + i*16 + quad*4 + r;
#pragma unroll
            for (int jd = 0; jd < 4; ++jd)
                out[rowg*DIM + h*DHEAD + jd*16 + lr] = f2bits(o[i][jd][r] * inv);
        }
}

// ---------- LayerNorm over DIM=512, fp32 in, bf16 out; one wave per row; float4 ----------
__global__ __launch_bounds__(256)
void ln_kernel(const float* __restrict__ x, const float* __restrict__ g,
               const float* __restrict__ b, u16* __restrict__ y, int rows)
{
    const int wave = threadIdx.x >> 6, lane = threadIdx.x & 63;
    const int row = blockIdx.x * 4 + wave;
    if (row >= rows) return;
    const float4* xr = (const float4*)(x + (size_t)row * DIM);
    float4 v0 = xr[lane], v1 = xr[lane + 64];
    float s  = v0.x+v0.y+v0.z+v0.w + v1.x+v1.y+v1.z+v1.w;
    float s2 = v0.x*v0.x+v0.y*v0.y+v0.z*v0.z+v0.w*v0.w
             + v1.x*v1.x+v1.y*v1.y+v1.z*v1.z+v1.w*v1.w;
#pragma unroll
    for (int off = 32; off; off >>= 1) { s += __shfl_xor(s, off); s2 += __shfl_xor(s2, off); }
    const float mean = s * (1.f/512.f);
    const float var  = s2 * (1.f/512.f) - mean*mean;
    const float rstd = rsqrtf(var + 1e-5f);
    const float4* gp = (const float4*)g; const float4* bp = (const float4*)b;
    float4 g0 = gp[lane], g1 = gp[lane+64], b0 = bp[lane], b1 = bp[lane+64];
    ushort4 o0, o1;
    o0.x = f2bits((v0.x-mean)*rstd*g0.x + b0.x);
    o0.y = f2bits((v0.y-mean)*rstd*g0.y + b0.y);
    o0.z = f2bits((v0.z-mean)*rstd*g0.z + b0.z);
    o0.w = f2bits((v0.w-mean)*rstd*g0.w + b0.w);
    o1.x = f2bits((v1.x-mean)*rstd*g1.x + b1.x);
    o1.y = f2bits((v1.y-mean)*rstd*g1.y + b1.y);
    o1.z = f2bits((v1.z-mean)*rstd*g1.z + b1.z);
    o1.w = f2bits((v1.w-mean)*rstd*g1.w + b1.w);
    ushort4* yr = (ushort4*)(y + (size_t)row * DIM);
    yr[lane] = o0; yr[lane+64] = o1;
}

// ---------- mean over P: [b,p,n,d] -> [b,n,d], 4 elems/thread ----------
__global__ void mean_kernel(const u16* __restrict__ L, u16* __restrict__ G)
{
    const int idx = blockIdx.x * 256 + threadIdx.x;
    const int b = idx >> 15;
    const int rem = idx & 32767;
    float a0 = 0.f, a1 = 0.f, a2 = 0.f, a3 = 0.f;
#pragma unroll
    for (int p = 0; p < PP; ++p) {
        ushort4 u = *(const ushort4*)(L + ((size_t)b*PP + p)*131072 + rem*4);
        a0 += bits2f(u.x); a1 += bits2f(u.y); a2 += bits2f(u.z); a3 += bits2f(u.w);
    }
    ushort4 o;
    o.x = f2bits(0.25f*a0); o.y = f2bits(0.25f*a1);
    o.z = f2bits(0.25f*a2); o.w = f2bits(0.25f*a3);
    *(ushort4*)(G + (size_t)idx*4) = o;
}

// ---------- s_attn: sigmoid( [xl, xg] . ws + bs ), one wave per row ----------
__global__ __launch_bounds__(256)
void sattn_kernel(const u16* __restrict__ xl, const u16* __restrict__ xg,
                  const float* __restrict__ wsv, const float* __restrict__ bs,
                  float* __restrict__ S)
{
    const int wave = threadIdx.x >> 6, lane = threadIdx.x & 63;
    const int row = blockIdx.x * 4 + wave;
    const int b = row >> 10;
    const int n = row & 255;
    const u16* xlr = xl + (size_t)row * RED;
    const u16* xgr = xg + ((size_t)b*NN + n) * RED;
    float s = bits2f(xlr[lane])    * wsv[lane]
            + bits2f(xlr[lane+64]) * wsv[lane+64]
            + bits2f(xgr[lane])    * wsv[RED+lane]
            + bits2f(xgr[lane+64]) * wsv[RED+64+lane];
#pragma unroll
    for (int off = 32; off; off >>= 1) s += __shfl_xor(s, off);
    if (lane == 0) S[row] = 1.f / (1.f + __expf(-(s + bs[0])));
}

// ---------- fuse: x_new = x_attn_res + mlp_out * c_attn * s_attn (4 elems/thread) ----------
__global__ void fuse_kernel(const float4* __restrict__ xb, const float4* __restrict__ m1,
                            const u16* __restrict__ ca, const float* __restrict__ S,
                            float4* __restrict__ xa)
{
    const int idx = blockIdx.x * 256 + threadIdx.x;
    const int r = idx >> 7;
    const int dg = idx & 127;
    const int b = r >> 10;
    const int n = r & 255;
    const float s = S[r];
    ushort4 cu = *(const ushort4*)(ca + ((((size_t)b << 8) + n)*DIM) + dg*4);
    float4 xv = xb[idx], mv = m1[idx], o;
    o.x = xv.x + mv.x * bits2f(cu.x) * s;
    o.y = xv.y + mv.y * bits2f(cu.y) * s;
    o.z = xv.z + mv.z * bits2f(cu.z) * s;
    o.w = xv.w + mv.w * bits2f(cu.w) * s;
    xa[idx] = o;
}

__global__ void copyf4_kernel(const float4* __restrict__ in, float4* __restrict__ out)
{
    const int idx = blockIdx.x * 256 + threadIdx.x;
    out[idx] = in[idx];
}

// ---------- host launch ----------
extern "C" void kernel_launch(void* const* d_in, const int* in_sizes, int n_in,
                              void* d_out, int out_size, void* d_ws, size_t ws_size,
                              hipStream_t stream)
{
    const float* x_in  = (const float*)d_in[0];
    const float* ln1_g = (const float*)d_in[1];
    const float* ln1_b = (const float*)d_in[2];
    const float* w_qkv = (const float*)d_in[3];
    const float* w_o   = (const float*)d_in[4];
    const float* b_o   = (const float*)d_in[5];
    const float* ln2_g = (const float*)d_in[6];
    const float* ln2_b = (const float*)d_in[7];
    const float* w1    = (const float*)d_in[8];
    const float* b1    = (const float*)d_in[9];
    const float* w2    = (const float*)d_in[10];
    const float* b2    = (const float*)d_in[11];
    const float* bn_g  = (const float*)d_in[12];
    const float* bn_b  = (const float*)d_in[13];
    const float* wg    = (const float*)d_in[14];
    const float* bg    = (const float*)d_in[15];
    const float* wl    = (const float*)d_in[16];
    const float* bl    = (const float*)d_in[17];
    const float* wc    = (const float*)d_in[18];
    const float* bc    = (const float*)d_in[19];
    const float* wsw   = (const float*)d_in[20];
    const float* bsb   = (const float*)d_in[21];

    char* ws = (char*)d_ws;
    auto alloc = [&](size_t bytes) {
        char* p = ws;
        ws += (bytes + 255) & ~(size_t)255;
        return p;
    };
    float* XA = (float*)alloc(XELEMS * 4);
    float* XB = (float*)alloc(XELEMS * 4);
    float* M1 = (float*)alloc(XELEMS * 4);
    u16*   L  = (u16*)  alloc(XELEMS * 2);
    u16*   Q  = (u16*)  alloc((size_t)ROWS * 3*DIM * 2);
    u16*   H  = (u16*)  alloc((size_t)ROWS * MLPD * 2);
    u16*   G  = (u16*)  alloc((size_t)BB*NN*DIM * 2);
    u16*   G2 = (u16*)  alloc((size_t)BB*NN*RED * 2);
    u16*   XL = (u16*)  alloc((size_t)ROWS*RED * 2);
    u16*   CA = (u16*)  alloc((size_t)BB*NN*DIM * 2);
    float* S  = (float*)alloc((size_t)ROWS * 4);
    u16* WTqkv = (u16*)alloc((size_t)DEPTH*DIM*3*DIM * 2);
    u16* WTo   = (u16*)alloc((size_t)DEPTH*DIM*DIM * 2);
    u16* WT1   = (u16*)alloc((size_t)DEPTH*DIM*MLPD * 2);
    u16* WT2   = (u16*)alloc((size_t)DEPTH*MLPD*DIM * 2);
    u16* WTl   = (u16*)alloc((size_t)DEPTH*DIM*RED * 2);
    u16* WTg   = (u16*)alloc((size_t)DEPTH*DIM*RED * 2);
    u16* WTc   = (u16*)alloc((size_t)DEPTH*RED*DIM * 2);

    wtrans_all<<<dim3(48,16,DEPTH), 256, 0, stream>>>(w_qkv, WTqkv, DIM, 3*DIM);
    wtrans_all<<<dim3(16,16,DEPTH), 256, 0, stream>>>(w_o,   WTo,   DIM, DIM);
    wtrans_all<<<dim3(64,16,DEPTH), 256, 0, stream>>>(w1,    WT1,   DIM, MLPD);
    wtrans_all<<<dim3(16,64,DEPTH), 256, 0, stream>>>(w2,    WT2,   MLPD, DIM);
    wtrans_all<<<dim3(4,16,DEPTH),  256, 0, stream>>>(wl,    WTl,   DIM, RED);
    wtrans_all<<<dim3(4,16,DEPTH),  256, 0, stream>>>(wg,    WTg,   DIM, RED);
    wtrans_all<<<dim3(16,4,DEPTH),  256, 0, stream>>>(wc,    WTc,   RED, DIM);

    copyf4_kernel<<<XELEMS/1024, 256, 0, stream>>>((const float4*)x_in, (float4*)XA);

    for (int l = 0; l < DEPTH; ++l) {
        // ---- attention block ----
        ln_kernel<<<ROWS/4, 256, 0, stream>>>(XA, ln1_g + l*DIM, ln1_b + l*DIM, L, ROWS);
        gemm_db<128,128,32,2,0,0><<<dim3(64,12), 256, 0, stream>>>(
            L, WTqkv + (size_t)l*DIM*3*DIM, nullptr, nullptr, Q, ROWS, 3*DIM, DIM);
        attn_mfma<<<BB*PP*HEADS, 256, 0, stream>>>(Q, L);
        gemm_db<64,128,64,2,1,0><<<dim3(128,4), 256, 0, stream>>>(
            L, WTo + (size_t)l*DIM*DIM, b_o + l*DIM, XA, XB, ROWS, DIM, DIM);

        // ---- MLP ----
        ln_kernel<<<ROWS/4, 256, 0, stream>>>(XB, ln2_g + l*DIM, ln2_b + l*DIM, Q, ROWS);
        gemm_db<128,128,32,2,0,1><<<dim3(64,16), 256, 0, stream>>>(
            Q, WT1 + (size_t)l*DIM*MLPD, b1 + l*MLPD, nullptr, H, ROWS, MLPD, DIM);
        gemm_db<64,128,64,2,1,0><<<dim3(128,4), 256, 0, stream>>>(
            H, WT2 + (size_t)l*MLPD*DIM, b2 + l*DIM, nullptr, M1, ROWS, DIM, MLPD);

        // ---- BiAttn ----
        ln_kernel<<<ROWS/4, 256, 0, stream>>>(M1, bn_g + l*DIM, bn_b + l*DIM, L, ROWS);
        mean_kernel<<<(BB*NN*DIM)/1024, 256, 0, stream>>>(L, G);
        gemm_db<64,64,64,2,0,1><<<dim3(32,2), 256, 0, stream>>>(
            G, WTg + (size_t)l*DIM*RED, bg + l*RED, nullptr, G2, BB*NN, RED, DIM);
        gemm_db<64,64,64,2,0,1><<<dim3(128,2), 256, 0, stream>>>(
            L, WTl + (size_t)l*DIM*RED, bl + l*RED, nullptr, XL, ROWS, RED, DIM);
        gemm_db<64,64,64,2,0,2><<<dim3(32,8), 256, 0, stream>>>(
            G2, WTc + (size_t)l*RED*DIM, bc + l*DIM, nullptr, CA, BB*NN, DIM, RED);
        sattn_kernel<<<ROWS/4, 256, 0, stream>>>(XL, G2, wsw + (size_t)l*2*RED, bsb + l, S);
        fuse_kernel<<<XELEMS/1024, 256, 0, stream>>>((const float4*)XB, (const float4*)M1,
                                                     CA, S, (float4*)XA);
    }

    copyf4_kernel<<<XELEMS/1024, 256, 0, stream>>>((const float4*)XA, (float4*)d_out);
}